// Round 17
// baseline (276.488 us; speedup 1.0000x reference)
//
#include <hip/hip_runtime.h>
#include <hip/hip_fp16.h>

typedef _Float16 half8v __attribute__((ext_vector_type(8)));
typedef __fp16  pk16x2 __attribute__((ext_vector_type(2)));
typedef float f32x4 __attribute__((ext_vector_type(4)));

#define DEV __device__ __forceinline__
DEV float crelu(float x) { return fminf(fmaxf(x, -1.0f), 1.0f); }

DEV unsigned int pkrtz_u32(float a, float b) {
    pk16x2 p = __builtin_amdgcn_cvt_pkrtz(a, b);
    return __builtin_bit_cast(unsigned int, p);
}

DEV void lgkm0() { asm volatile("s_waitcnt lgkmcnt(0)" ::: "memory"); }

// ---------------------------------------------------------------------------
// ws layout (r14):
//   floats [0, 1152): w1t/w2t legacy + w3t [16][2] @ 1120 (win L3, s_load)
//   byte 19200: f16 MFMA B-frags: L1 [3][64][8], L2 [64][8]
//   float 8192:  e1q [74][16] float4: row c, lane j -> {E1[j][c], E1[16+j][c],
//                E1[32+(j&1)][c], 0}; row 72 = xl col; row 73 = bias e1
//   float 13312: e2q [35][16] float4 (row 34 = bias e2)
//   float 15872: e3q [16] float4 {E3[j], E3[16+j], j<2?E3[32+j]:0, 0}
// ---------------------------------------------------------------------------
__global__ void prep_kernel(const float* __restrict__ W1, const float* __restrict__ W2,
                            const float* __restrict__ W3, const float* __restrict__ E1,
                            const float* __restrict__ E2, const float* __restrict__ e1b,
                            const float* __restrict__ e2b, const float* __restrict__ E3,
                            float* __restrict__ ws) {
    int t = threadIdx.x + blockIdx.x * blockDim.x;
    if (t < 864) {
        int s = t >> 4, o = t & 15;
        ws[t] = W1[o * 54 + s];
    } else if (t < 864 + 256) {
        int u = t - 864; int i = u >> 4, o = u & 15;
        ws[t] = W2[o * 16 + i];
    } else if (t < 1120 + 32) {
        int u = t - 1120; int i = u >> 1, o = u & 1;
        ws[t] = W3[o * 16 + i];
    } else if (t >= 8192 && t < 8192 + 1536) {
        _Float16* fr = (_Float16*)((char*)ws + 19200);
        int u = t - 8192;
        int ks = u >> 9, l = (u >> 3) & 63, j = u & 7;
        int n = l & 15;
        int kg = ks * 32 + ((l >> 4) << 3) + j;
        int ox = kg / 24, rem = kg - ox * 24, cy = rem >> 3, f = rem & 7;
        float v = (kg < 72 && f < 6) ? W1[n * 54 + ox * 18 + cy * 6 + f] : 0.0f;
        fr[u] = (_Float16)v;
    } else if (t >= 10240 && t < 10240 + 512) {
        _Float16* fr = (_Float16*)((char*)ws + 19200) + 1536;
        int u = t - 10240;
        int l = u >> 3, j = u & 7;
        int n = l & 15;
        int k = ((l >> 4) << 3) + j;
        float v = (k < 16) ? W2[n * 16 + k] : 0.0f;
        fr[u] = (_Float16)v;
    } else if (t >= 12288 && t < 12288 + 4736) {
        int u = t - 12288;
        int c = u >> 6, sl = u & 63, jj = sl >> 2, k = sl & 3;
        int o = (k == 0) ? jj : (k == 1) ? 16 + jj : 32 + (jj & 1);
        float v = 0.0f;
        if (k < 3) v = (c < 73) ? E1[o * 73 + c] : e1b[o];
        ws[8192 + u] = v;
    } else if (t >= 18432 && t < 18432 + 2240) {
        int u = t - 18432;
        int i = u >> 6, sl = u & 63, jj = sl >> 2, k = sl & 3;
        int o = (k == 0) ? jj : (k == 1) ? 16 + jj : 32 + (jj & 1);
        float v = 0.0f;
        if (k < 3) v = (i < 34) ? E2[o * 34 + i] : e2b[o];
        ws[13312 + u] = v;
    } else if (t >= 20992 && t < 20992 + 64) {
        int u = t - 20992;
        int jj = u >> 2, k = u & 3;
        float v = 0.0f;
        if (k == 0) v = E3[jj];
        else if (k == 1) v = E3[16 + jj];
        else if (k == 2) v = (jj < 2) ? E3[32 + jj] : 0.0f;
        ws[15872 + u] = v;
    }
}

// ---------------------------------------------------------------------------
// FUSED kernel: r14 win body (full LDS zero + lgkm0 fences) + r7 head tail.
// One wave = 4 elements. LDS per wave (689 half8):
//   grid[288] | h1[292] | visf[72] (288 f32) | xlf[1] (4 f32) | hbuf[36] (144 f32)
// Full-region zero also guarantees hbuf[es*36+34/35] == 0 (read, never written).
// Head: 16 lanes/element; lane j owns outputs {j, 16+j, 32+(j&1)}; E1/E2/E3
// weights from per-lane float4 tables (L1); h exchange via hbuf with lgkm0.
// ---------------------------------------------------------------------------
__global__ __launch_bounds__(256, 3) void fused_kernel(
    const float* __restrict__ inp,
    const float* __restrict__ b1, const float* __restrict__ b2,
    const float* __restrict__ b3, const float* __restrict__ e3v,
    const float* __restrict__ ws, const _Float16* __restrict__ frag,
    float* __restrict__ out)
{
    __shared__ half8v lds[4 * 689];          // 44096 B per 4-wave block
    const int tid  = threadIdx.x;
    const int wid  = tid >> 6;
    const int lane = tid & 63;
    const int baseP = (blockIdx.x * 4 + wid) * 4;

    half8v* grid = lds + wid * 689;          // 288
    half8v* h1   = grid + 288;               // 292
    _Float16* h1h = (_Float16*)h1;
    float* visf = (float*)(h1 + 292);        // 288 f32
    float* xlf  = visf + 288;                // 4 f32
    float* hbuf = visf + 292;                // 144 f32

    const int r = lane & 15;
    const int g = lane >> 4;

    // ---- zero the wave's whole LDS region (689 half8s) ----
    {
        const uint4 z = {0u, 0u, 0u, 0u};
        #pragma unroll
        for (int i = 0; i < 11; ++i) {
            const int idx = lane + i * 64;
            if (i < 10 || idx < 689)
                *reinterpret_cast<uint4*>(grid + idx) = z;
        }
    }
    lgkm0();

    // ---- stage 4 elements' grids + xl ----
    {
        const int es = lane >> 4, m = lane & 15;
        const float* __restrict__ src = inp + (size_t)(baseP + es) * 385 + 24 * m;
        #pragma unroll
        for (int c = 0; c < 4; ++c) {
            float f0 = src[c * 6 + 0], f1 = src[c * 6 + 1], f2 = src[c * 6 + 2];
            float f3 = src[c * 6 + 3], f4 = src[c * 6 + 4], f5 = src[c * 6 + 5];
            uint4 q;
            q.x = pkrtz_u32(f0, f1);
            q.y = pkrtz_u32(f2, f3);
            q.z = pkrtz_u32(f4, f5);
            q.w = q.z;                        // finite pad (zero-weighted)
            *reinterpret_cast<uint4*>(grid + es * 72 + 4 * m + c) = q;
        }
        if (m == 15) xlf[es] = src[24];       // inp[p*385 + 384]
    }
    lgkm0();                                  // staging writes -> cross-lane reads

    const half8v* __restrict__ fr8 = (const half8v*)frag;
    half8v B1_0 = fr8[0 * 64 + lane];
    half8v B1_1 = fr8[1 * 64 + lane];
    half8v B1_2 = fr8[2 * 64 + lane];
    half8v B2f  = fr8[3 * 64 + lane];

    int off[3];
    #pragma unroll
    for (int ks = 0; ks < 3; ++ks) {
        int c = ks * 4 + g;
        int ox = c / 3, cy = c - 3 * ox;
        off[ks] = ox * 8 + cy;
    }

    const float bias1 = b1[r];
    const float bias2 = b2[r];
    const float* __restrict__ w3t = ws + 1120;
    const float b30 = b3[0], b31 = b3[1];

    int w = r, ebase = 0;
    #pragma unroll
    for (int t = 0; t < 9; ++t) {
        const int x = (w * 43) >> 8;
        const int y = w - x * 6;
        const int cellb = ebase + x * 8 + y;

        half8v a0 = grid[cellb + off[0]];
        half8v a1 = grid[cellb + off[1]];
        half8v a2 = grid[cellb + off[2]];

        f32x4 acc = {bias1, bias1, bias1, bias1};
        acc = __builtin_amdgcn_mfma_f32_16x16x32_f16(a0, B1_0, acc, 0, 0, 0);
        acc = __builtin_amdgcn_mfma_f32_16x16x32_f16(a1, B1_1, acc, 0, 0, 0);
        acc = __builtin_amdgcn_mfma_f32_16x16x32_f16(a2, B1_2, acc, 0, 0, 0);

        #pragma unroll
        for (int q = 0; q < 4; ++q)
            h1h[(t * 16 + g * 4 + q) * 16 + r] = (_Float16)crelu(acc[q]);
        lgkm0();                              // h1 writes -> af read

        half8v af = h1[(t * 16 + r) * 2 + g];
        f32x4 c2 = {bias2, bias2, bias2, bias2};
        c2 = __builtin_amdgcn_mfma_f32_16x16x32_f16(af, B2f, c2, 0, 0, 0);

        #pragma unroll
        for (int q = 0; q < 4; ++q)
            h1h[(t * 16 + g * 4 + q) * 16 + r] = (_Float16)crelu(c2[q]);

        w += 16;
        if (w >= 36) { w -= 36; ebase += 72; }
    }
    lgkm0();                                  // h2 writes -> L3 reads

    // ---- layer 3 (VALU): vision -> visf (fp32, wave-private LDS) ----
    #pragma unroll
    for (int rep = 0; rep < 3; ++rep) {
        const int wg = lane + rep * 64;
        if (rep < 2 || lane < 16) {
            half8v ha = h1[wg * 2 + 0];
            half8v hb = h1[wg * 2 + 1];
            float v0 = b30, v1 = b31;
            #pragma unroll
            for (int i = 0; i < 8; ++i) {
                const float hv = (float)ha[i];
                v0 = fmaf(hv, w3t[i * 2 + 0], v0);
                v1 = fmaf(hv, w3t[i * 2 + 1], v1);
            }
            #pragma unroll
            for (int i = 0; i < 8; ++i) {
                const float hv = (float)hb[i];
                v0 = fmaf(hv, w3t[(8 + i) * 2 + 0], v0);
                v1 = fmaf(hv, w3t[(8 + i) * 2 + 1], v1);
            }
            float2 pv; pv.x = crelu(v0); pv.y = crelu(v1);
            *reinterpret_cast<float2*>(visf + wg * 2) = pv;   // visf[es*72+2w]
        }
    }
    lgkm0();                                  // vision writes -> head reads

    // ================== fused head (16 lanes per element) ==================
    const int es = lane >> 4, j = lane & 15;
    const float4* __restrict__ e1q = (const float4*)(ws + 8192);   // [74][16]
    const float4* __restrict__ e2q = (const float4*)(ws + 13312);  // [35][16]
    const float4* __restrict__ e3q = (const float4*)(ws + 15872);  // [16]

    float4 bi = e1q[73 * 16 + j];
    float a0 = bi.x, a1s = bi.y, a2s = bi.z;
    const float4* vp4f = (const float4*)(visf + es * 72);   // 18 x 16B
    #pragma unroll
    for (int cc = 0; cc < 18; ++cc) {
        const float4 q = vp4f[cc];
        #pragma unroll
        for (int u = 0; u < 4; ++u) {
            const float vx = (u == 0) ? q.x : (u == 1) ? q.y : (u == 2) ? q.z : q.w;
            const float4 wv = e1q[(cc * 4 + u) * 16 + j];
            a0  = fmaf(vx, wv.x, a0);
            a1s = fmaf(vx, wv.y, a1s);
            a2s = fmaf(vx, wv.z, a2s);
        }
    }
    {
        const float xv = xlf[es];
        const float4 wv = e1q[72 * 16 + j];
        a0  = fmaf(xv, wv.x, a0);
        a1s = fmaf(xv, wv.y, a1s);
        a2s = fmaf(xv, wv.z, a2s);
    }
    const float h0 = crelu(a0), h1c = crelu(a1s), h2c = crelu(a2s);
    hbuf[es * 36 + j]      = h0;
    hbuf[es * 36 + 16 + j] = h1c;
    if (j < 2) hbuf[es * 36 + 32 + j] = h2c;  // [34],[35] stay zero (pre-zeroed)
    lgkm0();                                  // hbuf writes -> gather reads

    float hh[36];
    {
        const float4* hp = (const float4*)(hbuf + es * 36);
        #pragma unroll
        for (int k = 0; k < 9; ++k) {
            const float4 q = hp[k];
            hh[4 * k + 0] = q.x; hh[4 * k + 1] = q.y;
            hh[4 * k + 2] = q.z; hh[4 * k + 3] = q.w;
        }
    }

    const float4 b2q = e2q[34 * 16 + j];
    float c0 = b2q.x, c1 = b2q.y, c2a = b2q.z;
    #pragma unroll
    for (int i = 0; i < 34; ++i) {
        const float4 wv = e2q[i * 16 + j];
        c0  = fmaf(hh[i], wv.x, c0);
        c1  = fmaf(hh[i], wv.y, c1);
        c2a = fmaf(hh[i], wv.z, c2a);
    }

    const float4 w3q = e3q[j];                // .z masked to lanes j<2
    float part = crelu(c0) * w3q.x + crelu(c1) * w3q.y + crelu(c2a) * w3q.z;
    part += __shfl_xor(part, 1);
    part += __shfl_xor(part, 2);
    part += __shfl_xor(part, 4);
    part += __shfl_xor(part, 8);
    if (j == 0) out[baseP + es] = crelu(part + e3v[0]);
}

extern "C" void kernel_launch(void* const* d_in, const int* in_sizes, int n_in,
                              void* d_out, int out_size, void* d_ws, size_t ws_size,
                              hipStream_t stream) {
    const float* inp = (const float*)d_in[0];
    const float* W1  = (const float*)d_in[1];
    const float* b1  = (const float*)d_in[2];
    const float* W2  = (const float*)d_in[3];
    const float* b2  = (const float*)d_in[4];
    const float* W3  = (const float*)d_in[5];
    const float* b3  = (const float*)d_in[6];
    const float* E1  = (const float*)d_in[7];
    const float* e1  = (const float*)d_in[8];
    const float* E2  = (const float*)d_in[9];
    const float* e2  = (const float*)d_in[10];
    const float* E3  = (const float*)d_in[11];
    const float* e3  = (const float*)d_in[12];
    float* out = (float*)d_out;
    float* ws  = (float*)d_ws;
    const _Float16* frag = (const _Float16*)((const char*)d_ws + 19200);

    prep_kernel<<<83, 256, 0, stream>>>(W1, W2, W3, E1, E2, e1, e2, E3, ws);

    const int B = 65536;
    // 4096 blocks x 4 waves x 4 elements = 65536
    fused_kernel<<<B / 16, 256, 0, stream>>>(inp, b1, b2, b3, e3, ws, frag, out);
}

// Round 18
// 186.152 us; speedup vs baseline: 1.4853x; 1.4853x over previous
//
#include <hip/hip_runtime.h>
#include <hip/hip_fp16.h>

typedef _Float16 half8v __attribute__((ext_vector_type(8)));
typedef __fp16  pk16x2 __attribute__((ext_vector_type(2)));
typedef float f32x4 __attribute__((ext_vector_type(4)));

#define DEV __device__ __forceinline__
DEV float crelu(float x) { return fminf(fmaxf(x, -1.0f), 1.0f); }

DEV unsigned int pkrtz_u32(float a, float b) {
    pk16x2 p = __builtin_amdgcn_cvt_pkrtz(a, b);
    return __builtin_bit_cast(unsigned int, p);
}

DEV void lgkm0() { asm volatile("s_waitcnt lgkmcnt(0)" ::: "memory"); }

// ---------------------------------------------------------------------------
// ws layout (r14):
//   floats [0, 1152): w1t/w2t legacy + w3t [16][2] @ 1120 (win L3, s_load)
//   byte 19200: f16 MFMA B-frags: L1 [3][64][8], L2 [64][8]
//   float 8192:  e1q [74][16] float4: row c, lane j -> {E1[j][c], E1[16+j][c],
//                E1[32+(j&1)][c], 0}; row 72 = xl col; row 73 = bias e1
//   float 13312: e2q [35][16] float4 (row 34 = bias e2)
//   float 15872: e3q [16] float4 {E3[j], E3[16+j], j<2?E3[32+j]:0, 0}
// ---------------------------------------------------------------------------
__global__ void prep_kernel(const float* __restrict__ W1, const float* __restrict__ W2,
                            const float* __restrict__ W3, const float* __restrict__ E1,
                            const float* __restrict__ E2, const float* __restrict__ e1b,
                            const float* __restrict__ e2b, const float* __restrict__ E3,
                            float* __restrict__ ws) {
    int t = threadIdx.x + blockIdx.x * blockDim.x;
    if (t < 864) {
        int s = t >> 4, o = t & 15;
        ws[t] = W1[o * 54 + s];
    } else if (t < 864 + 256) {
        int u = t - 864; int i = u >> 4, o = u & 15;
        ws[t] = W2[o * 16 + i];
    } else if (t < 1120 + 32) {
        int u = t - 1120; int i = u >> 1, o = u & 1;
        ws[t] = W3[o * 16 + i];
    } else if (t >= 8192 && t < 8192 + 1536) {
        _Float16* fr = (_Float16*)((char*)ws + 19200);
        int u = t - 8192;
        int ks = u >> 9, l = (u >> 3) & 63, j = u & 7;
        int n = l & 15;
        int kg = ks * 32 + ((l >> 4) << 3) + j;
        int ox = kg / 24, rem = kg - ox * 24, cy = rem >> 3, f = rem & 7;
        float v = (kg < 72 && f < 6) ? W1[n * 54 + ox * 18 + cy * 6 + f] : 0.0f;
        fr[u] = (_Float16)v;
    } else if (t >= 10240 && t < 10240 + 512) {
        _Float16* fr = (_Float16*)((char*)ws + 19200) + 1536;
        int u = t - 10240;
        int l = u >> 3, j = u & 7;
        int n = l & 15;
        int k = ((l >> 4) << 3) + j;
        float v = (k < 16) ? W2[n * 16 + k] : 0.0f;
        fr[u] = (_Float16)v;
    } else if (t >= 12288 && t < 12288 + 4736) {
        int u = t - 12288;
        int c = u >> 6, sl = u & 63, jj = sl >> 2, k = sl & 3;
        int o = (k == 0) ? jj : (k == 1) ? 16 + jj : 32 + (jj & 1);
        float v = 0.0f;
        if (k < 3) v = (c < 73) ? E1[o * 73 + c] : e1b[o];
        ws[8192 + u] = v;
    } else if (t >= 18432 && t < 18432 + 2240) {
        int u = t - 18432;
        int i = u >> 6, sl = u & 63, jj = sl >> 2, k = sl & 3;
        int o = (k == 0) ? jj : (k == 1) ? 16 + jj : 32 + (jj & 1);
        float v = 0.0f;
        if (k < 3) v = (i < 34) ? E2[o * 34 + i] : e2b[o];
        ws[13312 + u] = v;
    } else if (t >= 20992 && t < 20992 + 64) {
        int u = t - 20992;
        int jj = u >> 2, k = u & 3;
        float v = 0.0f;
        if (k == 0) v = E3[jj];
        else if (k == 1) v = E3[16 + jj];
        else if (k == 2) v = (jj < 2) ? E3[32 + jj] : 0.0f;
        ws[15872 + u] = v;
    }
}

// ---------------------------------------------------------------------------
// FUSED kernel (r17) with __launch_bounds__(256, 2): the r17 run kept the
// conv-era (256,3), capping VGPR at 84 -> the head tail (hh[36]+pipeline)
// spilled to scratch: 684 MB WRITE_SIZE, 276 us. Cap 128 VGPR fits the tail.
// ---------------------------------------------------------------------------
__global__ __launch_bounds__(256, 2) void fused_kernel(
    const float* __restrict__ inp,
    const float* __restrict__ b1, const float* __restrict__ b2,
    const float* __restrict__ b3, const float* __restrict__ e3v,
    const float* __restrict__ ws, const _Float16* __restrict__ frag,
    float* __restrict__ out)
{
    __shared__ half8v lds[4 * 689];          // 44096 B per 4-wave block
    const int tid  = threadIdx.x;
    const int wid  = tid >> 6;
    const int lane = tid & 63;
    const int baseP = (blockIdx.x * 4 + wid) * 4;

    half8v* grid = lds + wid * 689;          // 288
    half8v* h1   = grid + 288;               // 292
    _Float16* h1h = (_Float16*)h1;
    float* visf = (float*)(h1 + 292);        // 288 f32
    float* xlf  = visf + 288;                // 4 f32
    float* hbuf = visf + 292;                // 144 f32

    const int r = lane & 15;
    const int g = lane >> 4;

    // ---- zero the wave's whole LDS region (689 half8s) ----
    {
        const uint4 z = {0u, 0u, 0u, 0u};
        #pragma unroll
        for (int i = 0; i < 11; ++i) {
            const int idx = lane + i * 64;
            if (i < 10 || idx < 689)
                *reinterpret_cast<uint4*>(grid + idx) = z;
        }
    }
    lgkm0();

    // ---- stage 4 elements' grids + xl ----
    {
        const int es = lane >> 4, m = lane & 15;
        const float* __restrict__ src = inp + (size_t)(baseP + es) * 385 + 24 * m;
        #pragma unroll
        for (int c = 0; c < 4; ++c) {
            float f0 = src[c * 6 + 0], f1 = src[c * 6 + 1], f2 = src[c * 6 + 2];
            float f3 = src[c * 6 + 3], f4 = src[c * 6 + 4], f5 = src[c * 6 + 5];
            uint4 q;
            q.x = pkrtz_u32(f0, f1);
            q.y = pkrtz_u32(f2, f3);
            q.z = pkrtz_u32(f4, f5);
            q.w = q.z;                        // finite pad (zero-weighted)
            *reinterpret_cast<uint4*>(grid + es * 72 + 4 * m + c) = q;
        }
        if (m == 15) xlf[es] = src[24];       // inp[p*385 + 384]
    }
    lgkm0();                                  // staging writes -> cross-lane reads

    const half8v* __restrict__ fr8 = (const half8v*)frag;
    half8v B1_0 = fr8[0 * 64 + lane];
    half8v B1_1 = fr8[1 * 64 + lane];
    half8v B1_2 = fr8[2 * 64 + lane];
    half8v B2f  = fr8[3 * 64 + lane];

    int off[3];
    #pragma unroll
    for (int ks = 0; ks < 3; ++ks) {
        int c = ks * 4 + g;
        int ox = c / 3, cy = c - 3 * ox;
        off[ks] = ox * 8 + cy;
    }

    const float bias1 = b1[r];
    const float bias2 = b2[r];
    const float* __restrict__ w3t = ws + 1120;
    const float b30 = b3[0], b31 = b3[1];

    int w = r, ebase = 0;
    #pragma unroll
    for (int t = 0; t < 9; ++t) {
        const int x = (w * 43) >> 8;
        const int y = w - x * 6;
        const int cellb = ebase + x * 8 + y;

        half8v a0 = grid[cellb + off[0]];
        half8v a1 = grid[cellb + off[1]];
        half8v a2 = grid[cellb + off[2]];

        f32x4 acc = {bias1, bias1, bias1, bias1};
        acc = __builtin_amdgcn_mfma_f32_16x16x32_f16(a0, B1_0, acc, 0, 0, 0);
        acc = __builtin_amdgcn_mfma_f32_16x16x32_f16(a1, B1_1, acc, 0, 0, 0);
        acc = __builtin_amdgcn_mfma_f32_16x16x32_f16(a2, B1_2, acc, 0, 0, 0);

        #pragma unroll
        for (int q = 0; q < 4; ++q)
            h1h[(t * 16 + g * 4 + q) * 16 + r] = (_Float16)crelu(acc[q]);
        lgkm0();                              // h1 writes -> af read

        half8v af = h1[(t * 16 + r) * 2 + g];
        f32x4 c2 = {bias2, bias2, bias2, bias2};
        c2 = __builtin_amdgcn_mfma_f32_16x16x32_f16(af, B2f, c2, 0, 0, 0);

        #pragma unroll
        for (int q = 0; q < 4; ++q)
            h1h[(t * 16 + g * 4 + q) * 16 + r] = (_Float16)crelu(c2[q]);

        w += 16;
        if (w >= 36) { w -= 36; ebase += 72; }
    }
    lgkm0();                                  // h2 writes -> L3 reads

    // ---- layer 3 (VALU): vision -> visf (fp32, wave-private LDS) ----
    #pragma unroll
    for (int rep = 0; rep < 3; ++rep) {
        const int wg = lane + rep * 64;
        if (rep < 2 || lane < 16) {
            half8v ha = h1[wg * 2 + 0];
            half8v hb = h1[wg * 2 + 1];
            float v0 = b30, v1 = b31;
            #pragma unroll
            for (int i = 0; i < 8; ++i) {
                const float hv = (float)ha[i];
                v0 = fmaf(hv, w3t[i * 2 + 0], v0);
                v1 = fmaf(hv, w3t[i * 2 + 1], v1);
            }
            #pragma unroll
            for (int i = 0; i < 8; ++i) {
                const float hv = (float)hb[i];
                v0 = fmaf(hv, w3t[(8 + i) * 2 + 0], v0);
                v1 = fmaf(hv, w3t[(8 + i) * 2 + 1], v1);
            }
            float2 pv; pv.x = crelu(v0); pv.y = crelu(v1);
            *reinterpret_cast<float2*>(visf + wg * 2) = pv;   // visf[es*72+2w]
        }
    }
    lgkm0();                                  // vision writes -> head reads

    // ================== fused head (16 lanes per element) ==================
    const int es = lane >> 4, j = lane & 15;
    const float4* __restrict__ e1q = (const float4*)(ws + 8192);   // [74][16]
    const float4* __restrict__ e2q = (const float4*)(ws + 13312);  // [35][16]
    const float4* __restrict__ e3q = (const float4*)(ws + 15872);  // [16]

    float4 bi = e1q[73 * 16 + j];
    float a0 = bi.x, a1s = bi.y, a2s = bi.z;
    const float4* vp4f = (const float4*)(visf + es * 72);   // 18 x 16B
    #pragma unroll
    for (int cc = 0; cc < 18; ++cc) {
        const float4 q = vp4f[cc];
        #pragma unroll
        for (int u = 0; u < 4; ++u) {
            const float vx = (u == 0) ? q.x : (u == 1) ? q.y : (u == 2) ? q.z : q.w;
            const float4 wv = e1q[(cc * 4 + u) * 16 + j];
            a0  = fmaf(vx, wv.x, a0);
            a1s = fmaf(vx, wv.y, a1s);
            a2s = fmaf(vx, wv.z, a2s);
        }
    }
    {
        const float xv = xlf[es];
        const float4 wv = e1q[72 * 16 + j];
        a0  = fmaf(xv, wv.x, a0);
        a1s = fmaf(xv, wv.y, a1s);
        a2s = fmaf(xv, wv.z, a2s);
    }
    const float h0 = crelu(a0), h1c = crelu(a1s), h2c = crelu(a2s);
    hbuf[es * 36 + j]      = h0;
    hbuf[es * 36 + 16 + j] = h1c;
    if (j < 2) hbuf[es * 36 + 32 + j] = h2c;  // [34],[35] stay zero (pre-zeroed)
    lgkm0();                                  // hbuf writes -> gather reads

    float hh[36];
    {
        const float4* hp = (const float4*)(hbuf + es * 36);
        #pragma unroll
        for (int k = 0; k < 9; ++k) {
            const float4 q = hp[k];
            hh[4 * k + 0] = q.x; hh[4 * k + 1] = q.y;
            hh[4 * k + 2] = q.z; hh[4 * k + 3] = q.w;
        }
    }

    const float4 b2q = e2q[34 * 16 + j];
    float c0 = b2q.x, c1 = b2q.y, c2a = b2q.z;
    #pragma unroll
    for (int i = 0; i < 34; ++i) {
        const float4 wv = e2q[i * 16 + j];
        c0  = fmaf(hh[i], wv.x, c0);
        c1  = fmaf(hh[i], wv.y, c1);
        c2a = fmaf(hh[i], wv.z, c2a);
    }

    const float4 w3q = e3q[j];                // .z masked to lanes j<2
    float part = crelu(c0) * w3q.x + crelu(c1) * w3q.y + crelu(c2a) * w3q.z;
    part += __shfl_xor(part, 1);
    part += __shfl_xor(part, 2);
    part += __shfl_xor(part, 4);
    part += __shfl_xor(part, 8);
    if (j == 0) out[baseP + es] = crelu(part + e3v[0]);
}

extern "C" void kernel_launch(void* const* d_in, const int* in_sizes, int n_in,
                              void* d_out, int out_size, void* d_ws, size_t ws_size,
                              hipStream_t stream) {
    const float* inp = (const float*)d_in[0];
    const float* W1  = (const float*)d_in[1];
    const float* b1  = (const float*)d_in[2];
    const float* W2  = (const float*)d_in[3];
    const float* b2  = (const float*)d_in[4];
    const float* W3  = (const float*)d_in[5];
    const float* b3  = (const float*)d_in[6];
    const float* E1  = (const float*)d_in[7];
    const float* e1  = (const float*)d_in[8];
    const float* E2  = (const float*)d_in[9];
    const float* e2  = (const float*)d_in[10];
    const float* E3  = (const float*)d_in[11];
    const float* e3  = (const float*)d_in[12];
    float* out = (float*)d_out;
    float* ws  = (float*)d_ws;
    const _Float16* frag = (const _Float16*)((const char*)d_ws + 19200);

    prep_kernel<<<83, 256, 0, stream>>>(W1, W2, W3, E1, E2, e1, e2, E3, ws);

    const int B = 65536;
    // 4096 blocks x 4 waves x 4 elements = 65536
    fused_kernel<<<B / 16, 256, 0, stream>>>(inp, b1, b2, b3, e3, ws, frag, out);
}

// Round 19
// 43.886 us; speedup vs baseline: 6.3002x; 4.2417x over previous
//
#include <hip/hip_runtime.h>
#include <hip/hip_fp16.h>

typedef _Float16 half8v __attribute__((ext_vector_type(8)));
typedef __fp16  pk16x2 __attribute__((ext_vector_type(2)));
typedef float f32x4 __attribute__((ext_vector_type(4)));

#define DEV __device__ __forceinline__
DEV float crelu(float x) { return fminf(fmaxf(x, -1.0f), 1.0f); }

DEV unsigned int pkrtz_u32(float a, float b) {
    pk16x2 p = __builtin_amdgcn_cvt_pkrtz(a, b);
    return __builtin_bit_cast(unsigned int, p);
}

DEV void lgkm0() { asm volatile("s_waitcnt lgkmcnt(0)" ::: "memory"); }

// ---------------------------------------------------------------------------
// ws layout:
//   floats [0, 1152): w1t/w2t legacy + w3t [16][2] @ 1120 (win L3, s_load)
//   float 6000: e1bias48 | float 6048: e2bias48 | float 6096: e3p48
//   byte 19200: win f16 B-frags: L1 [3][64][8], L2 [64][8]
//   byte 32768: e1bf [3 ks][3 nt][64][8] f16 (9216 B)  E1^T B-frags, K=96
//               k<73 && o<34 ? E1[o*73+k] : 0   (k=72 is the xl column)
//   byte 45056: e2bf [2 ks][3 nt][64][8] f16 (6144 B)  E2^T B-frags, K=64
//   byte 65536: vbuf [B][36] half2 words (9.44 MB)  -- r14 layout, unchanged
// ---------------------------------------------------------------------------
__global__ void prep_kernel(const float* __restrict__ W1, const float* __restrict__ W2,
                            const float* __restrict__ W3, const float* __restrict__ E1,
                            const float* __restrict__ E2, const float* __restrict__ e1b,
                            const float* __restrict__ e2b, const float* __restrict__ E3,
                            float* __restrict__ ws) {
    int t = threadIdx.x + blockIdx.x * blockDim.x;
    if (t < 864) {
        int s = t >> 4, o = t & 15;
        ws[t] = W1[o * 54 + s];
    } else if (t < 864 + 256) {
        int u = t - 864; int i = u >> 4, o = u & 15;
        ws[t] = W2[o * 16 + i];
    } else if (t < 1120 + 32) {
        int u = t - 1120; int i = u >> 1, o = u & 1;
        ws[t] = W3[o * 16 + i];
    } else if (t >= 8192 && t < 8192 + 1536) {
        // win layer-1 B-frag
        _Float16* fr = (_Float16*)((char*)ws + 19200);
        int u = t - 8192;
        int ks = u >> 9, l = (u >> 3) & 63, j = u & 7;
        int n = l & 15;
        int kg = ks * 32 + ((l >> 4) << 3) + j;
        int ox = kg / 24, rem = kg - ox * 24, cy = rem >> 3, f = rem & 7;
        float v = (kg < 72 && f < 6) ? W1[n * 54 + ox * 18 + cy * 6 + f] : 0.0f;
        fr[u] = (_Float16)v;
    } else if (t >= 10240 && t < 10240 + 512) {
        // win layer-2 B-frag
        _Float16* fr = (_Float16*)((char*)ws + 19200) + 1536;
        int u = t - 10240;
        int l = u >> 3, j = u & 7;
        int n = l & 15;
        int k = ((l >> 4) << 3) + j;
        float v = (k < 16) ? W2[n * 16 + k] : 0.0f;
        fr[u] = (_Float16)v;
    } else if (t >= 12288 && t < 12288 + 4608) {
        // e1bf: K=96 (k=72 -> xl col, k>72 zero), N=48
        _Float16* fr = (_Float16*)((char*)ws + 32768);
        int u = t - 12288;
        int ks = u / 1536, rem = u % 1536;
        int nt = rem / 512;
        int l = (rem >> 3) & 63, j = u & 7;
        int k = ks * 32 + ((l >> 4) << 3) + j;
        int o = nt * 16 + (l & 15);
        float v = (k < 73 && o < 34) ? E1[o * 73 + k] : 0.0f;
        fr[u] = (_Float16)v;
    } else if (t >= 18432 && t < 18432 + 3072) {
        // e2bf: K=64 (k<34 valid), N=48
        _Float16* fr = (_Float16*)((char*)ws + 45056);
        int u = t - 18432;
        int ks = u / 1536, rem = u % 1536;
        int nt = rem / 512;
        int l = (rem >> 3) & 63, j = u & 7;
        int k = ks * 32 + ((l >> 4) << 3) + j;
        int o = nt * 16 + (l & 15);
        float v = (k < 34 && o < 34) ? E2[o * 34 + k] : 0.0f;
        fr[u] = (_Float16)v;
    } else if (t >= 22528 && t < 22528 + 48) {
        int u = t - 22528; ws[6000 + u] = (u < 34) ? e1b[u] : 0.0f;
    } else if (t >= 22592 && t < 22592 + 48) {
        int u = t - 22592; ws[6048 + u] = (u < 34) ? e2b[u] : 0.0f;
    } else if (t >= 22656 && t < 22656 + 48) {
        int u = t - 22656; ws[6096 + u] = (u < 34) ? E3[u] : 0.0f;
    }
}

// ---------------------------------------------------------------------------
// Phase 1 (MFMA conv): VERBATIM round-14 win_kernel (passed, 58.5us config).
// ---------------------------------------------------------------------------
__global__ __launch_bounds__(256, 3) void win_kernel(
    const float* __restrict__ inp,
    const float* __restrict__ b1, const float* __restrict__ b2,
    const float* __restrict__ b3,
    const float* __restrict__ ws, const _Float16* __restrict__ frag,
    unsigned int* __restrict__ vout)
{
    __shared__ half8v lds[4 * 580];
    const int tid  = threadIdx.x;
    const int wid  = tid >> 6;
    const int lane = tid & 63;
    const int baseP = (blockIdx.x * 4 + wid) * 4;

    half8v* grid = lds + wid * 580;
    half8v* h1   = grid + 288;
    _Float16* h1h = (_Float16*)h1;

    const int r = lane & 15;
    const int g = lane >> 4;

    // ---- zero the wave's whole LDS region (580 half8s) ----
    {
        const uint4 z = {0u, 0u, 0u, 0u};
        #pragma unroll
        for (int i = 0; i < 10; ++i) {
            const int idx = lane + i * 64;
            if (i < 9 || idx < 580)
                *reinterpret_cast<uint4*>(grid + idx) = z;
        }
    }
    lgkm0();

    // ---- stage 4 elements' grids ----
    {
        const int es = lane >> 4, m = lane & 15;
        const float* __restrict__ src = inp + (size_t)(baseP + es) * 385 + 24 * m;
        #pragma unroll
        for (int c = 0; c < 4; ++c) {
            float f0 = src[c * 6 + 0], f1 = src[c * 6 + 1], f2 = src[c * 6 + 2];
            float f3 = src[c * 6 + 3], f4 = src[c * 6 + 4], f5 = src[c * 6 + 5];
            uint4 q;
            q.x = pkrtz_u32(f0, f1);
            q.y = pkrtz_u32(f2, f3);
            q.z = pkrtz_u32(f4, f5);
            q.w = q.z;
            *reinterpret_cast<uint4*>(grid + es * 72 + 4 * m + c) = q;
        }
    }
    lgkm0();                                  // grid writes -> cross-lane reads

    const half8v* __restrict__ fr8 = (const half8v*)frag;
    half8v B1_0 = fr8[0 * 64 + lane];
    half8v B1_1 = fr8[1 * 64 + lane];
    half8v B1_2 = fr8[2 * 64 + lane];
    half8v B2f  = fr8[3 * 64 + lane];

    int off[3];
    #pragma unroll
    for (int ks = 0; ks < 3; ++ks) {
        int c = ks * 4 + g;
        int ox = c / 3, cy = c - 3 * ox;
        off[ks] = ox * 8 + cy;
    }

    const float bias1 = b1[r];
    const float bias2 = b2[r];
    const float* __restrict__ w3t = ws + 1120;
    const float b30 = b3[0], b31 = b3[1];

    int w = r, ebase = 0;
    #pragma unroll
    for (int t = 0; t < 9; ++t) {
        const int x = (w * 43) >> 8;
        const int y = w - x * 6;
        const int cellb = ebase + x * 8 + y;

        half8v a0 = grid[cellb + off[0]];
        half8v a1 = grid[cellb + off[1]];
        half8v a2 = grid[cellb + off[2]];

        f32x4 acc = {bias1, bias1, bias1, bias1};
        acc = __builtin_amdgcn_mfma_f32_16x16x32_f16(a0, B1_0, acc, 0, 0, 0);
        acc = __builtin_amdgcn_mfma_f32_16x16x32_f16(a1, B1_1, acc, 0, 0, 0);
        acc = __builtin_amdgcn_mfma_f32_16x16x32_f16(a2, B1_2, acc, 0, 0, 0);

        #pragma unroll
        for (int q = 0; q < 4; ++q)
            h1h[(t * 16 + g * 4 + q) * 16 + r] = (_Float16)crelu(acc[q]);
        lgkm0();                              // h1 writes -> af read

        half8v af = h1[(t * 16 + r) * 2 + g];
        f32x4 c2 = {bias2, bias2, bias2, bias2};
        c2 = __builtin_amdgcn_mfma_f32_16x16x32_f16(af, B2f, c2, 0, 0, 0);

        #pragma unroll
        for (int q = 0; q < 4; ++q)
            h1h[(t * 16 + g * 4 + q) * 16 + r] = (_Float16)crelu(c2[q]);

        w += 16;
        if (w >= 36) { w -= 36; ebase += 72; }
    }
    lgkm0();                                  // h2 writes -> L3 reads

    #pragma unroll
    for (int rep = 0; rep < 3; ++rep) {
        const int wg = lane + rep * 64;
        if (rep < 2 || lane < 16) {
            half8v ha = h1[wg * 2 + 0];
            half8v hb = h1[wg * 2 + 1];
            float v0 = b30, v1 = b31;
            #pragma unroll
            for (int i = 0; i < 8; ++i) {
                const float hv = (float)ha[i];
                v0 = fmaf(hv, w3t[i * 2 + 0], v0);
                v1 = fmaf(hv, w3t[i * 2 + 1], v1);
            }
            #pragma unroll
            for (int i = 0; i < 8; ++i) {
                const float hv = (float)hb[i];
                v0 = fmaf(hv, w3t[(8 + i) * 2 + 0], v0);
                v1 = fmaf(hv, w3t[(8 + i) * 2 + 1], v1);
            }
            vout[baseP * 36 + wg] = pkrtz_u32(crelu(v0), crelu(v1));
        }
    }
}

// ---------------------------------------------------------------------------
// Phase 2 (MFMA head, r10 design + NaN fix): one wave = 16 elements.
// E1: A rows = vbuf (72 vision halfs) + register-built tail (xl@72, zeros);
//     B = e1bf (K=96, N=48) -> 9 MFMA.
// h staged f16 in LDS hset[17][48]; WHOLE hset ZEROED first (r10's bug: E2's
// g>=2 A-frag reads run into row r+1; for r=15 that's row 16, never written
// -> stale NaN x 0-weight poisoned the accumulator).
// E2: A from LDS (K=64, k>=34 zero-B), B = e2bf -> 6 MFMA.
// E3: per-lane dot over 3 cols + 16-lane butterfly; lane r==0 stores float4.
// ---------------------------------------------------------------------------
__global__ __launch_bounds__(256) void head3b_kernel(
    const float* __restrict__ inp,
    const float* __restrict__ ws,
    const unsigned int* __restrict__ vbuf,
    const float* __restrict__ e3v,
    float* __restrict__ out)
{
    __shared__ _Float16 hset[4][17 * 48];    // 6528 B per block
    const int tid  = threadIdx.x;
    const int wid  = tid >> 6;
    const int lane = tid & 63;
    const int baseE = (blockIdx.x * 4 + wid) * 16;

    const int r = lane & 15;
    const int g = lane >> 4;
    _Float16* hw = hset[wid];

    // ---- zero the whole hset (102 uint4) ----
    {
        const uint4 z = {0u, 0u, 0u, 0u};
        if (lane < 51) {
            *reinterpret_cast<uint4*>(hw + lane * 8) = z;
            *reinterpret_cast<uint4*>(hw + (lane + 51) * 8) = z;
        }
    }
    lgkm0();

    const half8v* __restrict__ e1f8 = (const half8v*)((const char*)ws + 32768);
    const half8v* __restrict__ e2f8 = (const half8v*)((const char*)ws + 45056);

    // B-frags (wave-wide, L1-resident)
    half8v e1B[3][3], e2B[2][3];
    #pragma unroll
    for (int ks = 0; ks < 3; ++ks)
        #pragma unroll
        for (int nt = 0; nt < 3; ++nt)
            e1B[ks][nt] = e1f8[(ks * 3 + nt) * 64 + lane];
    #pragma unroll
    for (int ks = 0; ks < 2; ++ks)
        #pragma unroll
        for (int nt = 0; nt < 3; ++nt)
            e2B[ks][nt] = e2f8[(ks * 3 + nt) * 64 + lane];

    // per-lane biases / E3 weights (col o = nt*16 + r; o>=34 slots are 0)
    float biasA[3], bias2A[3], e3w[3];
    #pragma unroll
    for (int nt = 0; nt < 3; ++nt) {
        biasA[nt]  = ws[6000 + nt * 16 + r];
        bias2A[nt] = ws[6048 + nt * 16 + r];
        e3w[nt]    = ws[6096 + nt * 16 + r];
    }

    // ---- E1: 3 K-steps x 3 N-tiles; A row = element baseE + r ----
    const uint4* __restrict__ vp4 =
        (const uint4*)(vbuf + (size_t)(baseE + r) * 36);   // 9 uint4 of vision
    const float xl = inp[(size_t)(baseE + r) * 385 + 384];

    f32x4 acc[3] = {{biasA[0], biasA[0], biasA[0], biasA[0]},
                    {biasA[1], biasA[1], biasA[1], biasA[1]},
                    {biasA[2], biasA[2], biasA[2], biasA[2]}};
    #pragma unroll
    for (int ks = 0; ks < 3; ++ks) {
        uint4 aw;
        if (ks < 2) {
            aw = vp4[ks * 4 + g];            // halfs [ks*32+g*8, +8) of vision
        } else {
            if (g == 0)      aw = vp4[8];    // halfs 64..71
            else if (g == 1) { aw.x = pkrtz_u32(xl, 0.0f); aw.y = 0u; aw.z = 0u; aw.w = 0u; }
            else             { aw.x = 0u; aw.y = 0u; aw.z = 0u; aw.w = 0u; }
        }
        const half8v af = __builtin_bit_cast(half8v, aw);
        #pragma unroll
        for (int nt = 0; nt < 3; ++nt)
            acc[nt] = __builtin_amdgcn_mfma_f32_16x16x32_f16(af, e1B[ks][nt],
                                                             acc[nt], 0, 0, 0);
    }

    // ---- stage h = crelu(acc) to LDS [elem-row][48] f16 ----
    #pragma unroll
    for (int nt = 0; nt < 3; ++nt)
        #pragma unroll
        for (int q = 0; q < 4; ++q)
            hw[(g * 4 + q) * 48 + nt * 16 + r] = (_Float16)crelu(acc[nt][q]);
    lgkm0();                                  // h writes -> E2 A-frag reads

    // ---- E2: 2 K-steps x 3 N-tiles (k>=34 zero-B; overflow reads land in
    //      row r+1 / row 16, all finite: h values or zeroed pad) ----
    f32x4 acc2[3] = {{bias2A[0], bias2A[0], bias2A[0], bias2A[0]},
                     {bias2A[1], bias2A[1], bias2A[1], bias2A[1]},
                     {bias2A[2], bias2A[2], bias2A[2], bias2A[2]}};
    #pragma unroll
    for (int ks = 0; ks < 2; ++ks) {
        const half8v af = *reinterpret_cast<const half8v*>(
            &hw[r * 48 + ks * 32 + g * 8]);
        #pragma unroll
        for (int nt = 0; nt < 3; ++nt)
            acc2[nt] = __builtin_amdgcn_mfma_f32_16x16x32_f16(af, e2B[ks][nt],
                                                              acc2[nt], 0, 0, 0);
    }

    // ---- E3: per-lane partial over its 3 cols, butterfly over 16 lanes ----
    const float e3b = e3v[0];
    float s[4];
    #pragma unroll
    for (int q = 0; q < 4; ++q) {
        float part = crelu(acc2[0][q]) * e3w[0]
                   + crelu(acc2[1][q]) * e3w[1]
                   + crelu(acc2[2][q]) * e3w[2];
        part += __shfl_xor(part, 1);
        part += __shfl_xor(part, 2);
        part += __shfl_xor(part, 4);
        part += __shfl_xor(part, 8);
        s[q] = crelu(part + e3b);
    }
    if (r == 0) {
        float4 o4 = {s[0], s[1], s[2], s[3]};
        *reinterpret_cast<float4*>(out + baseE + g * 4) = o4;
    }
}

extern "C" void kernel_launch(void* const* d_in, const int* in_sizes, int n_in,
                              void* d_out, int out_size, void* d_ws, size_t ws_size,
                              hipStream_t stream) {
    const float* inp = (const float*)d_in[0];
    const float* W1  = (const float*)d_in[1];
    const float* b1  = (const float*)d_in[2];
    const float* W2  = (const float*)d_in[3];
    const float* b2  = (const float*)d_in[4];
    const float* W3  = (const float*)d_in[5];
    const float* b3  = (const float*)d_in[6];
    const float* E1  = (const float*)d_in[7];
    const float* e1  = (const float*)d_in[8];
    const float* E2  = (const float*)d_in[9];
    const float* e2  = (const float*)d_in[10];
    const float* E3  = (const float*)d_in[11];
    const float* e3  = (const float*)d_in[12];
    float* out = (float*)d_out;
    float* ws  = (float*)d_ws;
    const _Float16* frag = (const _Float16*)((const char*)d_ws + 19200);
    unsigned int* vbuf = (unsigned int*)((char*)d_ws + 65536);

    // prep threads up to 22704 -> 89 blocks
    prep_kernel<<<89, 256, 0, stream>>>(W1, W2, W3, E1, E2, e1, e2, E3, ws);

    const int B = 65536;
    win_kernel<<<B / 16, 256, 0, stream>>>(inp, b1, b2, b3, ws, frag, vbuf);
    // one wave per 16 elements
    head3b_kernel<<<B / 64, 256, 0, stream>>>(inp, ws, vbuf, e3, out);
}

// Round 20
// 42.832 us; speedup vs baseline: 6.4551x; 1.0246x over previous
//
#include <hip/hip_runtime.h>
#include <hip/hip_fp16.h>

typedef _Float16 half8v __attribute__((ext_vector_type(8)));
typedef __fp16  pk16x2 __attribute__((ext_vector_type(2)));
typedef float f32x4 __attribute__((ext_vector_type(4)));

#define DEV __device__ __forceinline__
DEV float crelu(float x) { return fminf(fmaxf(x, -1.0f), 1.0f); }

DEV unsigned int pkrtz_u32(float a, float b) {
    pk16x2 p = __builtin_amdgcn_cvt_pkrtz(a, b);
    return __builtin_bit_cast(unsigned int, p);
}

DEV void lgkm0() { asm volatile("s_waitcnt lgkmcnt(0)" ::: "memory"); }
// Compiler-only fence: per-wave DS ops execute in program order in HW
// (r6/r9 passed fence-free; correctness was decided only by the stale-LDS
// NaN issue, now fixed by deterministic zero-init). This just pins the
// compiler's ordering at zero runtime cost.
DEV void cfence() { asm volatile("" ::: "memory"); }

// ---------------------------------------------------------------------------
// ws layout:
//   floats [0, 1152): w1t/w2t legacy + w3t [16][2] @ 1120 (win L3, s_load)
//   float 6000: e1bias48 | float 6048: e2bias48 | float 6096: e3p48
//   byte 19200: win f16 B-frags: L1 [3][64][8], L2 [64][8]
//   byte 32768: e1bf [3 ks][3 nt][64][8] f16 (9216 B)  E1^T B-frags, K=96
//   byte 45056: e2bf [2 ks][3 nt][64][8] f16 (6144 B)  E2^T B-frags, K=64
//   byte 65536: vbuf [B][36] half2 words (9.44 MB)
// ---------------------------------------------------------------------------
__global__ void prep_kernel(const float* __restrict__ W1, const float* __restrict__ W2,
                            const float* __restrict__ W3, const float* __restrict__ E1,
                            const float* __restrict__ E2, const float* __restrict__ e1b,
                            const float* __restrict__ e2b, const float* __restrict__ E3,
                            float* __restrict__ ws) {
    int t = threadIdx.x + blockIdx.x * blockDim.x;
    if (t < 864) {
        int s = t >> 4, o = t & 15;
        ws[t] = W1[o * 54 + s];
    } else if (t < 864 + 256) {
        int u = t - 864; int i = u >> 4, o = u & 15;
        ws[t] = W2[o * 16 + i];
    } else if (t < 1120 + 32) {
        int u = t - 1120; int i = u >> 1, o = u & 1;
        ws[t] = W3[o * 16 + i];
    } else if (t >= 8192 && t < 8192 + 1536) {
        // win layer-1 B-frag
        _Float16* fr = (_Float16*)((char*)ws + 19200);
        int u = t - 8192;
        int ks = u >> 9, l = (u >> 3) & 63, j = u & 7;
        int n = l & 15;
        int kg = ks * 32 + ((l >> 4) << 3) + j;
        int ox = kg / 24, rem = kg - ox * 24, cy = rem >> 3, f = rem & 7;
        float v = (kg < 72 && f < 6) ? W1[n * 54 + ox * 18 + cy * 6 + f] : 0.0f;
        fr[u] = (_Float16)v;
    } else if (t >= 10240 && t < 10240 + 512) {
        // win layer-2 B-frag
        _Float16* fr = (_Float16*)((char*)ws + 19200) + 1536;
        int u = t - 10240;
        int l = u >> 3, j = u & 7;
        int n = l & 15;
        int k = ((l >> 4) << 3) + j;
        float v = (k < 16) ? W2[n * 16 + k] : 0.0f;
        fr[u] = (_Float16)v;
    } else if (t >= 12288 && t < 12288 + 4608) {
        // e1bf: K=96 (k=72 -> xl col, k>72 zero), N=48
        _Float16* fr = (_Float16*)((char*)ws + 32768);
        int u = t - 12288;
        int ks = u / 1536, rem = u % 1536;
        int nt = rem / 512;
        int l = (rem >> 3) & 63, j = u & 7;
        int k = ks * 32 + ((l >> 4) << 3) + j;
        int o = nt * 16 + (l & 15);
        float v = (k < 73 && o < 34) ? E1[o * 73 + k] : 0.0f;
        fr[u] = (_Float16)v;
    } else if (t >= 18432 && t < 18432 + 3072) {
        // e2bf: K=64 (k<34 valid), N=48
        _Float16* fr = (_Float16*)((char*)ws + 45056);
        int u = t - 18432;
        int ks = u / 1536, rem = u % 1536;
        int nt = rem / 512;
        int l = (rem >> 3) & 63, j = u & 7;
        int k = ks * 32 + ((l >> 4) << 3) + j;
        int o = nt * 16 + (l & 15);
        float v = (k < 34 && o < 34) ? E2[o * 34 + k] : 0.0f;
        fr[u] = (_Float16)v;
    } else if (t >= 22528 && t < 22528 + 48) {
        int u = t - 22528; ws[6000 + u] = (u < 34) ? e1b[u] : 0.0f;
    } else if (t >= 22592 && t < 22592 + 48) {
        int u = t - 22592; ws[6048 + u] = (u < 34) ? e2b[u] : 0.0f;
    } else if (t >= 22656 && t < 22656 + 48) {
        int u = t - 22656; ws[6096 + u] = (u < 34) ? E3[u] : 0.0f;
    }
}

// ---------------------------------------------------------------------------
// Phase 1 (MFMA conv): r14/r19 win_kernel with hardware lgkmcnt waits
// replaced by compiler-only fences (single change this round). Full LDS
// zero-init retained (deterministic 0-weighted pad reads).
// ---------------------------------------------------------------------------
__global__ __launch_bounds__(256, 3) void win_kernel(
    const float* __restrict__ inp,
    const float* __restrict__ b1, const float* __restrict__ b2,
    const float* __restrict__ b3,
    const float* __restrict__ ws, const _Float16* __restrict__ frag,
    unsigned int* __restrict__ vout)
{
    __shared__ half8v lds[4 * 580];
    const int tid  = threadIdx.x;
    const int wid  = tid >> 6;
    const int lane = tid & 63;
    const int baseP = (blockIdx.x * 4 + wid) * 4;

    half8v* grid = lds + wid * 580;
    half8v* h1   = grid + 288;
    _Float16* h1h = (_Float16*)h1;

    const int r = lane & 15;
    const int g = lane >> 4;

    // ---- zero the wave's whole LDS region (580 half8s) ----
    {
        const uint4 z = {0u, 0u, 0u, 0u};
        #pragma unroll
        for (int i = 0; i < 10; ++i) {
            const int idx = lane + i * 64;
            if (i < 9 || idx < 580)
                *reinterpret_cast<uint4*>(grid + idx) = z;
        }
    }
    cfence();

    // ---- stage 4 elements' grids ----
    {
        const int es = lane >> 4, m = lane & 15;
        const float* __restrict__ src = inp + (size_t)(baseP + es) * 385 + 24 * m;
        #pragma unroll
        for (int c = 0; c < 4; ++c) {
            float f0 = src[c * 6 + 0], f1 = src[c * 6 + 1], f2 = src[c * 6 + 2];
            float f3 = src[c * 6 + 3], f4 = src[c * 6 + 4], f5 = src[c * 6 + 5];
            uint4 q;
            q.x = pkrtz_u32(f0, f1);
            q.y = pkrtz_u32(f2, f3);
            q.z = pkrtz_u32(f4, f5);
            q.w = q.z;
            *reinterpret_cast<uint4*>(grid + es * 72 + 4 * m + c) = q;
        }
    }
    cfence();                                 // staging writes -> cross-lane reads

    const half8v* __restrict__ fr8 = (const half8v*)frag;
    half8v B1_0 = fr8[0 * 64 + lane];
    half8v B1_1 = fr8[1 * 64 + lane];
    half8v B1_2 = fr8[2 * 64 + lane];
    half8v B2f  = fr8[3 * 64 + lane];

    int off[3];
    #pragma unroll
    for (int ks = 0; ks < 3; ++ks) {
        int c = ks * 4 + g;
        int ox = c / 3, cy = c - 3 * ox;
        off[ks] = ox * 8 + cy;
    }

    const float bias1 = b1[r];
    const float bias2 = b2[r];
    const float* __restrict__ w3t = ws + 1120;
    const float b30 = b3[0], b31 = b3[1];

    int w = r, ebase = 0;
    #pragma unroll
    for (int t = 0; t < 9; ++t) {
        const int x = (w * 43) >> 8;
        const int y = w - x * 6;
        const int cellb = ebase + x * 8 + y;

        half8v a0 = grid[cellb + off[0]];
        half8v a1 = grid[cellb + off[1]];
        half8v a2 = grid[cellb + off[2]];

        f32x4 acc = {bias1, bias1, bias1, bias1};
        acc = __builtin_amdgcn_mfma_f32_16x16x32_f16(a0, B1_0, acc, 0, 0, 0);
        acc = __builtin_amdgcn_mfma_f32_16x16x32_f16(a1, B1_1, acc, 0, 0, 0);
        acc = __builtin_amdgcn_mfma_f32_16x16x32_f16(a2, B1_2, acc, 0, 0, 0);

        #pragma unroll
        for (int q = 0; q < 4; ++q)
            h1h[(t * 16 + g * 4 + q) * 16 + r] = (_Float16)crelu(acc[q]);
        cfence();                             // h1 writes -> af read

        half8v af = h1[(t * 16 + r) * 2 + g];
        f32x4 c2 = {bias2, bias2, bias2, bias2};
        c2 = __builtin_amdgcn_mfma_f32_16x16x32_f16(af, B2f, c2, 0, 0, 0);

        #pragma unroll
        for (int q = 0; q < 4; ++q)
            h1h[(t * 16 + g * 4 + q) * 16 + r] = (_Float16)crelu(c2[q]);

        w += 16;
        if (w >= 36) { w -= 36; ebase += 72; }
    }
    cfence();                                 // h2 writes -> L3 reads

    #pragma unroll
    for (int rep = 0; rep < 3; ++rep) {
        const int wg = lane + rep * 64;
        if (rep < 2 || lane < 16) {
            half8v ha = h1[wg * 2 + 0];
            half8v hb = h1[wg * 2 + 1];
            float v0 = b30, v1 = b31;
            #pragma unroll
            for (int i = 0; i < 8; ++i) {
                const float hv = (float)ha[i];
                v0 = fmaf(hv, w3t[i * 2 + 0], v0);
                v1 = fmaf(hv, w3t[i * 2 + 1], v1);
            }
            #pragma unroll
            for (int i = 0; i < 8; ++i) {
                const float hv = (float)hb[i];
                v0 = fmaf(hv, w3t[(8 + i) * 2 + 0], v0);
                v1 = fmaf(hv, w3t[(8 + i) * 2 + 1], v1);
            }
            vout[baseP * 36 + wg] = pkrtz_u32(crelu(v0), crelu(v1));
        }
    }
}

// ---------------------------------------------------------------------------
// Phase 2 (MFMA head): VERBATIM round-19 head3b (passed).
// ---------------------------------------------------------------------------
__global__ __launch_bounds__(256) void head3b_kernel(
    const float* __restrict__ inp,
    const float* __restrict__ ws,
    const unsigned int* __restrict__ vbuf,
    const float* __restrict__ e3v,
    float* __restrict__ out)
{
    __shared__ _Float16 hset[4][17 * 48];    // 6528 B per block
    const int tid  = threadIdx.x;
    const int wid  = tid >> 6;
    const int lane = tid & 63;
    const int baseE = (blockIdx.x * 4 + wid) * 16;

    const int r = lane & 15;
    const int g = lane >> 4;
    _Float16* hw = hset[wid];

    // ---- zero the whole hset (102 uint4) ----
    {
        const uint4 z = {0u, 0u, 0u, 0u};
        if (lane < 51) {
            *reinterpret_cast<uint4*>(hw + lane * 8) = z;
            *reinterpret_cast<uint4*>(hw + (lane + 51) * 8) = z;
        }
    }
    lgkm0();

    const half8v* __restrict__ e1f8 = (const half8v*)((const char*)ws + 32768);
    const half8v* __restrict__ e2f8 = (const half8v*)((const char*)ws + 45056);

    half8v e1B[3][3], e2B[2][3];
    #pragma unroll
    for (int ks = 0; ks < 3; ++ks)
        #pragma unroll
        for (int nt = 0; nt < 3; ++nt)
            e1B[ks][nt] = e1f8[(ks * 3 + nt) * 64 + lane];
    #pragma unroll
    for (int ks = 0; ks < 2; ++ks)
        #pragma unroll
        for (int nt = 0; nt < 3; ++nt)
            e2B[ks][nt] = e2f8[(ks * 3 + nt) * 64 + lane];

    float biasA[3], bias2A[3], e3w[3];
    #pragma unroll
    for (int nt = 0; nt < 3; ++nt) {
        biasA[nt]  = ws[6000 + nt * 16 + r];
        bias2A[nt] = ws[6048 + nt * 16 + r];
        e3w[nt]    = ws[6096 + nt * 16 + r];
    }

    const uint4* __restrict__ vp4 =
        (const uint4*)(vbuf + (size_t)(baseE + r) * 36);
    const float xl = inp[(size_t)(baseE + r) * 385 + 384];

    f32x4 acc[3] = {{biasA[0], biasA[0], biasA[0], biasA[0]},
                    {biasA[1], biasA[1], biasA[1], biasA[1]},
                    {biasA[2], biasA[2], biasA[2], biasA[2]}};
    #pragma unroll
    for (int ks = 0; ks < 3; ++ks) {
        uint4 aw;
        if (ks < 2) {
            aw = vp4[ks * 4 + g];
        } else {
            if (g == 0)      aw = vp4[8];
            else if (g == 1) { aw.x = pkrtz_u32(xl, 0.0f); aw.y = 0u; aw.z = 0u; aw.w = 0u; }
            else             { aw.x = 0u; aw.y = 0u; aw.z = 0u; aw.w = 0u; }
        }
        const half8v af = __builtin_bit_cast(half8v, aw);
        #pragma unroll
        for (int nt = 0; nt < 3; ++nt)
            acc[nt] = __builtin_amdgcn_mfma_f32_16x16x32_f16(af, e1B[ks][nt],
                                                             acc[nt], 0, 0, 0);
    }

    #pragma unroll
    for (int nt = 0; nt < 3; ++nt)
        #pragma unroll
        for (int q = 0; q < 4; ++q)
            hw[(g * 4 + q) * 48 + nt * 16 + r] = (_Float16)crelu(acc[nt][q]);
    lgkm0();

    f32x4 acc2[3] = {{bias2A[0], bias2A[0], bias2A[0], bias2A[0]},
                     {bias2A[1], bias2A[1], bias2A[1], bias2A[1]},
                     {bias2A[2], bias2A[2], bias2A[2], bias2A[2]}};
    #pragma unroll
    for (int ks = 0; ks < 2; ++ks) {
        const half8v af = *reinterpret_cast<const half8v*>(
            &hw[r * 48 + ks * 32 + g * 8]);
        #pragma unroll
        for (int nt = 0; nt < 3; ++nt)
            acc2[nt] = __builtin_amdgcn_mfma_f32_16x16x32_f16(af, e2B[ks][nt],
                                                              acc2[nt], 0, 0, 0);
    }

    const float e3b = e3v[0];
    float s[4];
    #pragma unroll
    for (int q = 0; q < 4; ++q) {
        float part = crelu(acc2[0][q]) * e3w[0]
                   + crelu(acc2[1][q]) * e3w[1]
                   + crelu(acc2[2][q]) * e3w[2];
        part += __shfl_xor(part, 1);
        part += __shfl_xor(part, 2);
        part += __shfl_xor(part, 4);
        part += __shfl_xor(part, 8);
        s[q] = crelu(part + e3b);
    }
    if (r == 0) {
        float4 o4 = {s[0], s[1], s[2], s[3]};
        *reinterpret_cast<float4*>(out + baseE + g * 4) = o4;
    }
}

extern "C" void kernel_launch(void* const* d_in, const int* in_sizes, int n_in,
                              void* d_out, int out_size, void* d_ws, size_t ws_size,
                              hipStream_t stream) {
    const float* inp = (const float*)d_in[0];
    const float* W1  = (const float*)d_in[1];
    const float* b1  = (const float*)d_in[2];
    const float* W2  = (const float*)d_in[3];
    const float* b2  = (const float*)d_in[4];
    const float* W3  = (const float*)d_in[5];
    const float* b3  = (const float*)d_in[6];
    const float* E1  = (const float*)d_in[7];
    const float* e1  = (const float*)d_in[8];
    const float* E2  = (const float*)d_in[9];
    const float* e2  = (const float*)d_in[10];
    const float* E3  = (const float*)d_in[11];
    const float* e3  = (const float*)d_in[12];
    float* out = (float*)d_out;
    float* ws  = (float*)d_ws;
    const _Float16* frag = (const _Float16*)((const char*)d_ws + 19200);
    unsigned int* vbuf = (unsigned int*)((char*)d_ws + 65536);

    prep_kernel<<<89, 256, 0, stream>>>(W1, W2, W3, E1, E2, e1, e2, E3, ws);

    const int B = 65536;
    win_kernel<<<B / 16, 256, 0, stream>>>(inp, b1, b2, b3, ws, frag, vbuf);
    head3b_kernel<<<B / 64, 256, 0, stream>>>(inp, ws, vbuf, e3, out);
}